// Round 32
// baseline (50.720 us; speedup 1.0000x reference)
//
#include <hip/hip_runtime.h>

#define NMOL   32
#define NATOM  512
#define NPAIR  32768
#define NB     64
#define HIDDEN 256
#define TOTNATOM (NMOL * NATOM)
#define NSUB   8
#define BLKCAP4 4352   // all-valid records/block (4096 + slack), LDS SoA
#define BLKCAP2 2816   // compacted 8B records/block (global stride)
#define NSLOT  48      // per-atom compacted slots (lambda 17, +7 sigma)

typedef __attribute__((ext_vector_type(8))) short bf16x8;
typedef __attribute__((ext_vector_type(4))) float f32x4;

__device__ __forceinline__ unsigned short f2bf(float x) {   // RNE f32->bf16
    unsigned u = __float_as_uint(x);
    u += 0x7FFFu + ((u >> 16) & 1u);
    return (unsigned short)(u >> 16);
}

// ---------------------------------------------------------------------------
// K1 scatter: verbatim R31 (SoA 12B list, direct compacted emit, 67KB LDS).
// ---------------------------------------------------------------------------
__global__ __launch_bounds__(1024) void scatter_kernel(
    const float* __restrict__ cart, const float* __restrict__ shifts,
    const int* __restrict__ species, const int* __restrict__ atom_index,
    unsigned* __restrict__ cnt, unsigned* __restrict__ soff_g,
    float2* __restrict__ rec, float* __restrict__ tv_part,
    float* __restrict__ dipole, int ndip)
{
    __shared__ float    s_cart[NATOM * 3];  // 6 KB
    __shared__ int      s_sp[NATOM];        // 2 KB
    __shared__ unsigned lcnt[NATOM];        // 2 KB
    __shared__ unsigned pref[NATOM];        // 2 KB
    __shared__ unsigned ccnt[NATOM];        // 2 KB
    __shared__ unsigned pref2[NATOM];       // 2 KB
    __shared__ float    lx[BLKCAP4];        // 17 KB
    __shared__ float    ly[BLKCAP4];        // 17 KB
    __shared__ float    lz[BLKCAP4];        // 17 KB (spc in 3 LSBs)

    const int tid  = threadIdx.x;
    const int lane = tid & 63;
    const int wave = tid >> 6;
    const int b    = blockIdx.x;
    const int mol  = b & 31;               // XCD swizzle (R29)
    const int sub  = b >> 5;

    if (b == 0 && tid < ndip) dipole[tid] = 0.f;

    const float* cm = cart + (size_t)mol * NATOM * 3;
    const int*   sp = species + (size_t)mol * NATOM;
    for (int i = tid; i < NATOM * 3; i += 1024) s_cart[i] = cm[i];
    if (tid < NATOM) { lcnt[tid] = 0u; s_sp[tid] = sp[tid]; }
    __syncthreads();

    const int* ai0 = atom_index + (size_t)mol * NPAIR;
    const int* ai1 = ai0 + (size_t)NMOL * NPAIR;
    const float* sh = shifts + (size_t)mol * NPAIR * 3;
    const int base = sub * 4096;

    int   gi0[4], gi1[4];
    float gsx[4], gsy[4], gsz[4];
#pragma unroll
    for (int k = 0; k < 4; ++k) {              // batched global loads
        const int p = base + k * 1024 + tid;
        gi0[k] = ai0[p];
        gi1[k] = ai1[p];
        gsx[k] = sh[p * 3 + 0];
        gsy[k] = sh[p * 3 + 1];
        gsz[k] = sh[p * 3 + 2];
    }

    float    rx[4], ry[4], rz[4];
    unsigned rs[4], rp[4];
    int      ri[4];
#pragma unroll
    for (int k = 0; k < 4; ++k) {
        const int a3 = gi0[k] * 3, b3 = gi1[k] * 3;
        const bool m = (gsx[k] > -1e10f && gsy[k] > -1e10f && gsz[k] > -1e10f);
        ri[k] = -1;
        if (m) {                               // masked pairs contribute nothing
            rx[k] = s_cart[a3 + 0] - s_cart[b3 + 0] + gsx[k];
            ry[k] = s_cart[a3 + 1] - s_cart[b3 + 1] + gsy[k];
            rz[k] = s_cart[a3 + 2] - s_cart[b3 + 2] + gsz[k];
            rs[k] = (unsigned)s_sp[gi1[k]];
            ri[k] = gi0[k];
            rp[k] = atomicAdd(&lcnt[gi0[k]], 1u);   // rtn = within-atom ordinal
        }
    }
    __syncthreads();

    if (wave == 0) {                           // scan lcnt -> pref (exclusive)
        unsigned c[8], s = 0;
#pragma unroll
        for (int j = 0; j < 8; ++j) { c[j] = lcnt[lane * 8 + j]; s += c[j]; }
        unsigned incl = s;
#pragma unroll
        for (int off = 1; off < 64; off <<= 1) {
            const unsigned v = __shfl_up(incl, off);
            if (lane >= off) incl += v;
        }
        unsigned run = incl - s;
#pragma unroll
        for (int j = 0; j < 8; ++j) { pref[lane * 8 + j] = run; run += c[j]; }
    }
    __syncthreads();

#pragma unroll
    for (int k = 0; k < 4; ++k) {              // pass 2: group all-valid (SoA)
        if (ri[k] >= 0) {
            const unsigned idx = pref[ri[k]] + rp[k];
            if (idx < (unsigned)BLKCAP4) {
                lx[idx] = rx[k];
                ly[idx] = ry[k];
                lz[idx] = __uint_as_float((__float_as_uint(rz[k]) & ~7u) | rs[k]);
            }
        }
    }
    __syncthreads();

    // walk1: thread = atom; tv segment-sum + in-cutoff count (atomic-free)
    if (tid < NATOM) {
        const int a  = tid;
        const int j0 = (int)pref[a];
        const int j1 = min(j0 + (int)lcnt[a], BLKCAP4);
        float tx = 0.f, ty = 0.f, tz = 0.f;
        unsigned c2 = 0;
        for (int j = j0; j < j1; ++j) {
            const float x = lx[j], y = ly[j], z = lz[j];
            tx += x; ty += y; tz += z;
            const float d = sqrtf(x * x + y * y + z * z + 1e-12f);
            if (d < 5.0f) ++c2;
        }
        ccnt[a] = c2;
        float* tg = tv_part + ((size_t)b * NATOM + a) * 3;
        tg[0] = tx; tg[1] = ty; tg[2] = tz;
    }
    __syncthreads();

    if (wave == 0) {                           // scan ccnt -> pref2
        unsigned c[8], s = 0;
#pragma unroll
        for (int j = 0; j < 8; ++j) { c[j] = ccnt[lane * 8 + j]; s += c[j]; }
        unsigned incl = s;
#pragma unroll
        for (int off = 1; off < 64; off <<= 1) {
            const unsigned v = __shfl_up(incl, off);
            if (lane >= off) incl += v;
        }
        unsigned run = incl - s;
#pragma unroll
        for (int j = 0; j < 8; ++j) { pref2[lane * 8 + j] = run; run += c[j]; }
    }
    __syncthreads();

    // walk2: thread = atom; emit compacted 8B {d, fc|spc} DIRECT to global
    if (tid < NATOM) {
        const int a  = tid;
        const int j0 = (int)pref[a];
        const int j1 = min(j0 + (int)lcnt[a], BLKCAP4);
        unsigned w = pref2[a];
        float2* dstr = rec + (size_t)b * BLKCAP2;
        for (int j = j0; j < j1; ++j) {
            const float x = lx[j], y = ly[j], z = lz[j];
            const float d = sqrtf(x * x + y * y + z * z + 1e-12f);
            if (d < 5.0f) {
                const float fc = 0.5f * (__cosf(0.62831853071795864769f * d) + 1.f);
                const unsigned fb = (__float_as_uint(fc) & ~7u)
                                  | (__float_as_uint(z) & 7u);
                if (w < (unsigned)BLKCAP2)
                    dstr[w] = make_float2(d, __uint_as_float(fb));
                ++w;
            }
        }
        cnt[((size_t)mol * NATOM + a) * NSUB + sub] = ccnt[a];
        soff_g[(size_t)b * NATOM + a] = pref2[a];
    }
}

// ---------------------------------------------------------------------------
// K2 gnn: gather + MFMA-nn fused. 256 blocks x 256 thr, 64 atoms/block,
// XCD-swizzled. SAFE NOW: both phases are the lean R31 forms (no per-thread
// arrays > 12 regs; past fusion failures were 1024-thr spills / min-waves
// hints / 61KB-at-4-wave LDS). Records staged in TWO 32-atom halves (list2
// reused, 12.3KB); density lives only in LDS (dens_bf + tvv round-trips and
// one dispatch boundary deleted). ~66KB LDS.
// ---------------------------------------------------------------------------
__global__ __launch_bounds__(256) void gnn_kernel(
    const unsigned* __restrict__ cnt, const unsigned* __restrict__ soff_g,
    const float2* __restrict__ rec,
    const float* __restrict__ centers, const float* __restrict__ widths,
    const float* __restrict__ c_emb, const float* __restrict__ tv_part,
    const float* __restrict__ W1, const float* __restrict__ b1,
    const float* __restrict__ W2, const float* __restrict__ b2,
    float* __restrict__ dipole)
{
    __shared__ __align__(16) unsigned short w1t[HIDDEN * 72];   // 36.9 KB
    __shared__ float    b1_l[HIDDEN], w2_l[HIDDEN];             // 2 KB
    __shared__ float    cemb[8 * NB];                           // 2 KB
    __shared__ __align__(16) unsigned short dens_l[64][72];     // 9.2 KB
    __shared__ float    tv_l[64 * 3];                           // 768 B
    __shared__ float2   list2[32][NSLOT];                       // 12.3 KB (per half)
    __shared__ unsigned scnt[32][NSUB];                         // 1 KB
    __shared__ unsigned sofg[32][NSUB];                         // 1 KB
    __shared__ unsigned soff[32][NSUB];                         // 1 KB
    __shared__ unsigned mtot[32];
    __shared__ float    sred[4][4][3];

    const int tid   = threadIdx.x;
    const int B     = blockIdx.x;
    const int mol   = B & 31;                  // XCD swizzle
    const int chunk = B >> 5;                  // 0..7
    const int a0    = mol * NATOM + chunk * 64;
    const int ra0   = chunk * 64;

    for (int i = tid; i < NB * HIDDEN; i += 256) {      // stage W1^T as bf16
        const int k = i >> 8, j = i & 255;              // coalesced f32 reads
        w1t[j * 72 + k] = f2bf(W1[i]);
    }
    if (tid < HIDDEN) { b1_l[tid] = b1[tid]; w2_l[tid] = W2[tid]; }
    for (int i = tid; i < 8 * NB; i += 256) cemb[i] = c_emb[i];

    const int lane = tid & 63;
    const int wave = tid >> 6;
    const float L2E = 1.4426950408889634f;
    const float wl  = widths[lane];
    const float cl  = centers[lane];
    const float qe  = -wl * L2E;
    const float qb  = 2.f * wl * cl * L2E;
    const float qa  = -wl * cl * cl * L2E;

    // ---- gather: two 32-atom halves (list2/meta reused across halves) ----
    for (int half = 0; half < 2; ++half) {
        const int ab = half * 32;              // local atom base
        __syncthreads();                       // WAR: list2/meta vs prev phase B

        {   // meta: 256 (atom, sub) entries, one per thread (cnt coalesced)
            const int al = tid >> 3, s = tid & 7;
            scnt[al][s] = cnt[(size_t)(a0 + ab + al) * NSUB + s];
            sofg[al][s] = soff_g[(size_t)(s * NMOL + mol) * NATOM + (ra0 + ab + al)];
        }
        __syncthreads();

        if (tid < 32) {                        // per-atom prefix + zero-pad
            int o = 0;
#pragma unroll
            for (int s = 0; s < NSUB; ++s) {
                soff[tid][s] = (unsigned)o;
                o += min((int)scnt[tid][s], NSLOT - o);
            }
            const int mp = (o + 7) & ~7;
            mtot[tid] = (unsigned)(mp <= NSLOT ? mp : NSLOT & ~7);
            for (int k = o; k < mp && k < NSLOT; ++k)
                list2[tid][k] = make_float2(0.f, 0.f);
        }
        if (tid >= 128 && tid < 128 + 96) {    // tv: 32 atoms x 3 comps
            const int t = tid - 128;
            const int al = t / 3, c = t - al * 3;
            float s = 0.f;
#pragma unroll
            for (int sb = 0; sb < NSUB; ++sb)
                s += tv_part[((size_t)(sb * NMOL + mol) * NATOM + (ra0 + ab + al)) * 3 + c];
            tv_l[(ab + al) * 3 + c] = s;
        }
        __syncthreads();

        {   // segment copy: 1 thread per (atom, sub) segment (256 segments)
            const int al = tid >> 3, s = tid & 7;
            const int off = (int)soff[al][s];
            const int n = min((int)scnt[al][s], NSLOT - off);
            const float2* src = rec + (size_t)(s * NMOL + mol) * BLKCAP2 + sofg[al][s];
            float2* dst = &list2[al][off];
            for (int k = 0; k < n; ++k) dst[k] = src[k];
        }
        __syncthreads();

        // phase B: wave handles 8 atoms of this half (lane = basis)
#define REC1(A, dv, fv) { const unsigned f_ = __float_as_uint(fv);           \
        const float v_ = fmaf(dv, fmaf(dv, qe, qb), qa);                     \
        A = fmaf(exp2f(v_) * __uint_as_float(f_ & ~7u),                      \
                 cemb[((f_ & 7u) << 6) | lane], A); }
        for (int al = wave; al < 32; al += 4) {
            const int mp = (int)mtot[al];
            const float4* l4 = reinterpret_cast<const float4*>(list2[al]);
            float acc0 = 0.f, acc1 = 0.f;
            for (int j = 0; j < mp; j += 8) {
                const float4 q0 = l4[(j >> 1) + 0];
                const float4 q1 = l4[(j >> 1) + 1];
                const float4 q2 = l4[(j >> 1) + 2];
                const float4 q3 = l4[(j >> 1) + 3];
                REC1(acc0, q0.x, q0.y) REC1(acc1, q0.z, q0.w)
                REC1(acc0, q1.x, q1.y) REC1(acc1, q1.z, q1.w)
                REC1(acc0, q2.x, q2.y) REC1(acc1, q2.z, q2.w)
                REC1(acc0, q3.x, q3.y) REC1(acc1, q3.z, q3.w)
            }
            dens_l[ab + al][lane] = f2bf(acc0 + acc1);
        }
#undef REC1
    }
    __syncthreads();

    // ---- nn: MFMA from LDS density (verbatim R31 structure) ----
    {
        const int fr = lane & 15;
        const int fg = lane >> 4;
        const int lbase = wave * 16;           // wave's 16-atom local M-tile

        bf16x8 afr[2];
#pragma unroll
        for (int kk = 0; kk < 2; ++kk)
            afr[kk] = *reinterpret_cast<const bf16x8*>(
                &dens_l[lbase + fr][kk * 32 + fg * 8]);

        float sdip[4] = {0.f, 0.f, 0.f, 0.f};
#pragma unroll
        for (int nt = 0; nt < 16; ++nt) {
            const bf16x8 bf0 = *reinterpret_cast<const bf16x8*>(
                &w1t[(nt * 16 + fr) * 72 + 0 + fg * 8]);
            const bf16x8 bf1 = *reinterpret_cast<const bf16x8*>(
                &w1t[(nt * 16 + fr) * 72 + 32 + fg * 8]);
            f32x4 acc = {0.f, 0.f, 0.f, 0.f};
            acc = __builtin_amdgcn_mfma_f32_16x16x32_bf16(afr[0], bf0, acc, 0, 0, 0);
            acc = __builtin_amdgcn_mfma_f32_16x16x32_bf16(afr[1], bf1, acc, 0, 0, 0);
            const int j = nt * 16 + fr;
            const float b1v = b1_l[j], w2v = w2_l[j];
#pragma unroll
            for (int i = 0; i < 4; ++i) {      // silu * W2, accumulate
                const float h = acc[i] + b1v;
                sdip[i] += (h / (1.f + __expf(-h))) * w2v;
            }
        }
#pragma unroll
        for (int off = 1; off < 16; off <<= 1) {   // reduce over 16 j-cols
#pragma unroll
            for (int i = 0; i < 4; ++i) sdip[i] += __shfl_xor(sdip[i], off);
        }
        if (fr == 0) {                         // local rows lbase + fg*4 + i
            const float b2v = b2[0];
            float px = 0.f, py = 0.f, pz = 0.f;
#pragma unroll
            for (int i = 0; i < 4; ++i) {
                const int la = lbase + fg * 4 + i;
                const float out = sdip[i] + b2v;
                px += out * tv_l[la * 3 + 0];
                py += out * tv_l[la * 3 + 1];
                pz += out * tv_l[la * 3 + 2];
            }
            sred[wave][fg][0] = px; sred[wave][fg][1] = py; sred[wave][fg][2] = pz;
        }
        __syncthreads();
        if (tid < 3) {
            float s = 0.f;
#pragma unroll
            for (int w = 0; w < 4; ++w)
#pragma unroll
                for (int g = 0; g < 4; ++g) s += sred[w][g][tid];
            unsafeAtomicAdd(&dipole[mol * 3 + tid], s);
        }
    }
}

// ---------------------------------------------------------------------------
extern "C" void kernel_launch(void* const* d_in, const int* in_sizes, int n_in,
                              void* d_out, int out_size, void* d_ws, size_t ws_size,
                              hipStream_t stream)
{
    const float* cart       = (const float*)d_in[0];
    const float* shifts     = (const float*)d_in[1];
    const float* centers    = (const float*)d_in[2];
    const float* widths     = (const float*)d_in[3];
    const float* c_emb      = (const float*)d_in[4];
    const float* W1         = (const float*)d_in[5];
    const float* b1         = (const float*)d_in[6];
    const float* W2         = (const float*)d_in[7];
    const float* b2         = (const float*)d_in[8];
    const int*   species    = (const int*)d_in[10];
    const int*   atom_index = (const int*)d_in[11];

    // ws: cnt(512KB) | soff_g(512KB) | tv_part(1.5MB) | rec(5.8MB)
    unsigned* cnt     = (unsigned*)d_ws;
    unsigned* soff_g  = cnt + (size_t)TOTNATOM * NSUB;
    float*    tv_part = (float*)(soff_g + (size_t)NMOL * NSUB * NATOM);
    float2*   rec     = (float2*)(tv_part + (size_t)NMOL * NSUB * NATOM * 3);
    float*    dipole  = (float*)d_out;

    hipLaunchKernelGGL(scatter_kernel, dim3(NMOL * NSUB), dim3(1024), 0, stream,
                       cart, shifts, species, atom_index, cnt, soff_g, rec,
                       tv_part, dipole, out_size);
    hipLaunchKernelGGL(gnn_kernel, dim3(NMOL * NSUB), dim3(256), 0, stream,
                       cnt, soff_g, rec, centers, widths, c_emb, tv_part,
                       W1, b1, W2, b2, dipole);
}

// Round 33
// 40.869 us; speedup vs baseline: 1.2410x; 1.2410x over previous
//
#include <hip/hip_runtime.h>

#define NMOL   32
#define NATOM  512
#define NPAIR  32768
#define NB     64
#define HIDDEN 256
#define TOTNATOM (NMOL * NATOM)
#define NSUB   8
#define BLKCAP4 4352   // all-valid records/block (4096 + slack), LDS SoA
#define BLKCAP2 2816   // compacted 8B records/block (global stride)
#define ABLK   4
#define NSLOT  48      // per-atom compacted slots in gather (lambda 17, +7 sigma)

typedef __attribute__((ext_vector_type(8))) short bf16x8;
typedef __attribute__((ext_vector_type(4))) float f32x4;

__device__ __forceinline__ unsigned short f2bf(float x) {   // RNE f32->bf16
    unsigned u = __float_as_uint(x);
    u += 0x7FFFu + ((u >> 16) & 1u);
    return (unsigned short)(u >> 16);
}

// ---------------------------------------------------------------------------
// K1 scatter: R31 final. SoA 12B LDS list (spc packed in lz's 3 mantissa
// LSBs), atomic-free walks, direct compacted 8B record emit. The only LDS
// atomic is lcnt (R26 ablation: fp32 LDS atomics were ~17us of the original
// 20.6us scatter -- throughput ~1 lane-op/3cyc/CU).
// ---------------------------------------------------------------------------
__global__ __launch_bounds__(1024) void scatter_kernel(
    const float* __restrict__ cart, const float* __restrict__ shifts,
    const int* __restrict__ species, const int* __restrict__ atom_index,
    unsigned* __restrict__ cnt, unsigned* __restrict__ soff_g,
    float2* __restrict__ rec, float* __restrict__ tv_part,
    float* __restrict__ dipole, int ndip)
{
    __shared__ float    s_cart[NATOM * 3];  // 6 KB
    __shared__ int      s_sp[NATOM];        // 2 KB
    __shared__ unsigned lcnt[NATOM];        // 2 KB
    __shared__ unsigned pref[NATOM];        // 2 KB
    __shared__ unsigned ccnt[NATOM];        // 2 KB
    __shared__ unsigned pref2[NATOM];       // 2 KB
    __shared__ float    lx[BLKCAP4];        // 17 KB
    __shared__ float    ly[BLKCAP4];        // 17 KB
    __shared__ float    lz[BLKCAP4];        // 17 KB (spc in 3 LSBs)

    const int tid  = threadIdx.x;
    const int lane = tid & 63;
    const int wave = tid >> 6;
    const int b    = blockIdx.x;
    const int mol  = b & 31;               // XCD swizzle (R29)
    const int sub  = b >> 5;

    if (b == 0 && tid < ndip) dipole[tid] = 0.f;

    const float* cm = cart + (size_t)mol * NATOM * 3;
    const int*   sp = species + (size_t)mol * NATOM;
    for (int i = tid; i < NATOM * 3; i += 1024) s_cart[i] = cm[i];
    if (tid < NATOM) { lcnt[tid] = 0u; s_sp[tid] = sp[tid]; }
    __syncthreads();

    const int* ai0 = atom_index + (size_t)mol * NPAIR;
    const int* ai1 = ai0 + (size_t)NMOL * NPAIR;
    const float* sh = shifts + (size_t)mol * NPAIR * 3;
    const int base = sub * 4096;

    int   gi0[4], gi1[4];
    float gsx[4], gsy[4], gsz[4];
#pragma unroll
    for (int k = 0; k < 4; ++k) {              // batched global loads
        const int p = base + k * 1024 + tid;
        gi0[k] = ai0[p];
        gi1[k] = ai1[p];
        gsx[k] = sh[p * 3 + 0];
        gsy[k] = sh[p * 3 + 1];
        gsz[k] = sh[p * 3 + 2];
    }

    float    rx[4], ry[4], rz[4];
    unsigned rs[4], rp[4];
    int      ri[4];
#pragma unroll
    for (int k = 0; k < 4; ++k) {
        const int a3 = gi0[k] * 3, b3 = gi1[k] * 3;
        const bool m = (gsx[k] > -1e10f && gsy[k] > -1e10f && gsz[k] > -1e10f);
        ri[k] = -1;
        if (m) {                               // masked pairs contribute nothing
            rx[k] = s_cart[a3 + 0] - s_cart[b3 + 0] + gsx[k];
            ry[k] = s_cart[a3 + 1] - s_cart[b3 + 1] + gsy[k];
            rz[k] = s_cart[a3 + 2] - s_cart[b3 + 2] + gsz[k];
            rs[k] = (unsigned)s_sp[gi1[k]];
            ri[k] = gi0[k];
            rp[k] = atomicAdd(&lcnt[gi0[k]], 1u);   // rtn = within-atom ordinal
        }
    }
    __syncthreads();

    if (wave == 0) {                           // scan lcnt -> pref (exclusive)
        unsigned c[8], s = 0;
#pragma unroll
        for (int j = 0; j < 8; ++j) { c[j] = lcnt[lane * 8 + j]; s += c[j]; }
        unsigned incl = s;
#pragma unroll
        for (int off = 1; off < 64; off <<= 1) {
            const unsigned v = __shfl_up(incl, off);
            if (lane >= off) incl += v;
        }
        unsigned run = incl - s;
#pragma unroll
        for (int j = 0; j < 8; ++j) { pref[lane * 8 + j] = run; run += c[j]; }
    }
    __syncthreads();

#pragma unroll
    for (int k = 0; k < 4; ++k) {              // pass 2: group all-valid (SoA)
        if (ri[k] >= 0) {
            const unsigned idx = pref[ri[k]] + rp[k];
            if (idx < (unsigned)BLKCAP4) {
                lx[idx] = rx[k];
                ly[idx] = ry[k];
                lz[idx] = __uint_as_float((__float_as_uint(rz[k]) & ~7u) | rs[k]);
            }
        }
    }
    __syncthreads();

    // walk1: thread = atom; tv segment-sum + in-cutoff count (atomic-free)
    if (tid < NATOM) {
        const int a  = tid;
        const int j0 = (int)pref[a];
        const int j1 = min(j0 + (int)lcnt[a], BLKCAP4);
        float tx = 0.f, ty = 0.f, tz = 0.f;
        unsigned c2 = 0;
        for (int j = j0; j < j1; ++j) {
            const float x = lx[j], y = ly[j], z = lz[j];
            tx += x; ty += y; tz += z;
            const float d = sqrtf(x * x + y * y + z * z + 1e-12f);
            if (d < 5.0f) ++c2;
        }
        ccnt[a] = c2;
        float* tg = tv_part + ((size_t)b * NATOM + a) * 3;
        tg[0] = tx; tg[1] = ty; tg[2] = tz;
    }
    __syncthreads();

    if (wave == 0) {                           // scan ccnt -> pref2
        unsigned c[8], s = 0;
#pragma unroll
        for (int j = 0; j < 8; ++j) { c[j] = ccnt[lane * 8 + j]; s += c[j]; }
        unsigned incl = s;
#pragma unroll
        for (int off = 1; off < 64; off <<= 1) {
            const unsigned v = __shfl_up(incl, off);
            if (lane >= off) incl += v;
        }
        unsigned run = incl - s;
#pragma unroll
        for (int j = 0; j < 8; ++j) { pref2[lane * 8 + j] = run; run += c[j]; }
    }
    __syncthreads();

    // walk2: thread = atom; emit compacted 8B {d, fc|spc} DIRECT to global
    if (tid < NATOM) {
        const int a  = tid;
        const int j0 = (int)pref[a];
        const int j1 = min(j0 + (int)lcnt[a], BLKCAP4);
        unsigned w = pref2[a];
        float2* dstr = rec + (size_t)b * BLKCAP2;
        for (int j = j0; j < j1; ++j) {
            const float x = lx[j], y = ly[j], z = lz[j];
            const float d = sqrtf(x * x + y * y + z * z + 1e-12f);
            if (d < 5.0f) {
                const float fc = 0.5f * (__cosf(0.62831853071795864769f * d) + 1.f);
                const unsigned fb = (__float_as_uint(fc) & ~7u)
                                  | (__float_as_uint(z) & 7u);
                if (w < (unsigned)BLKCAP2)
                    dstr[w] = make_float2(d, __uint_as_float(fb));
                ++w;
            }
        }
        cnt[((size_t)mol * NATOM + a) * NSUB + sub] = ccnt[a];
        soff_g[(size_t)b * NATOM + a] = pref2[a];
    }
}

// ---------------------------------------------------------------------------
// K2 gather: R31 final. 4096 blocks x 256 thr, 4 atoms/block, XCD-swizzled.
// Compacted records -> tiny copies + phase B + tv partial sums.
// ---------------------------------------------------------------------------
__global__ __launch_bounds__(256) void gather_kernel(
    const unsigned* __restrict__ cnt, const unsigned* __restrict__ soff_g,
    const float2* __restrict__ rec,
    const float* __restrict__ centers, const float* __restrict__ widths,
    const float* __restrict__ c_emb, const float* __restrict__ tv_part,
    unsigned short* __restrict__ dens_bf, float* __restrict__ tvv)
{
    __shared__ float    cemb[8 * NB];          // 2 KB
    __shared__ float2   list2[ABLK][NSLOT];    // 1.5 KB
    __shared__ unsigned scnt[ABLK][NSUB];
    __shared__ unsigned sofg[ABLK][NSUB];
    __shared__ unsigned soff[ABLK][NSUB];
    __shared__ unsigned mtot[ABLK];

    const int tid   = threadIdx.x;
    const int B     = blockIdx.x;
    const int mol   = B & 31;                  // XCD swizzle
    const int inner = B >> 5;                  // 0..127
    const int a0    = mol * NATOM + inner * ABLK;
    const int ra0   = inner * ABLK;

    for (int i = tid; i < 8 * NB; i += 256) cemb[i] = c_emb[i];
    if (tid < ABLK * NSUB) {                   // 32 loads
        const int al = tid >> 3, s = tid & 7;
        scnt[al][s] = cnt[(size_t)(a0 + al) * NSUB + s];
        sofg[al][s] = soff_g[(size_t)(s * NMOL + mol) * NATOM + (ra0 + al)];
    }
    __syncthreads();

    if (tid < ABLK) {                          // per-atom prefix + zero-pad
        int o = 0;
#pragma unroll
        for (int s = 0; s < NSUB; ++s) {
            soff[tid][s] = (unsigned)o;
            o += min((int)scnt[tid][s], NSLOT - o);
        }
        const int mp = (o + 7) & ~7;           // pad to multiple of 8
        mtot[tid] = (unsigned)(mp <= NSLOT ? mp : NSLOT & ~7);
        for (int k = o; k < mp && k < NSLOT; ++k)
            list2[tid][k] = make_float2(0.f, 0.f);
    }
    __syncthreads();

    {   // segment copy: 8 threads per (atom, sub) segment (32 segments)
        const int seg = tid >> 3;              // 0..31
        const int prt = tid & 7;
        const int al = seg >> 3, s = seg & 7;
        const int off = (int)soff[al][s];
        const int n = min((int)scnt[al][s], NSLOT - off);
        const float2* src = rec + (size_t)(s * NMOL + mol) * BLKCAP2 + sofg[al][s];
        float2* dst = &list2[al][off];
        for (int k = prt; k < n; k += 8) dst[k] = src[k];
    }
    if (tid < ABLK * 3) {                      // tv: sum the 8 block-partials
        const int al = tid / 3, c = tid - al * 3;
        float s = 0.f;
#pragma unroll
        for (int sb = 0; sb < NSUB; ++sb)
            s += tv_part[((size_t)(sb * NMOL + mol) * NATOM + (ra0 + al)) * 3 + c];
        tvv[(size_t)(a0 + al) * 3 + c] = s;
    }
    __syncthreads();

    const int lane = tid & 63;
    const int al   = tid >> 6;                 // wave = atom
    const int a    = a0 + al;

    const float L2E = 1.4426950408889634f;
    const float wl  = widths[lane];
    const float cl  = centers[lane];
    const float qe  = -wl * L2E;
    const float qb  = 2.f * wl * cl * L2E;
    const float qa  = -wl * cl * cl * L2E;

    // ---- phase B: lane = basis ----
#define REC1(A, dv, fv) { const unsigned f_ = __float_as_uint(fv);           \
        const float v_ = fmaf(dv, fmaf(dv, qe, qb), qa);                     \
        A = fmaf(exp2f(v_) * __uint_as_float(f_ & ~7u),                      \
                 cemb[((f_ & 7u) << 6) | lane], A); }
    const int mp = (int)mtot[al];
    const float4* l4 = reinterpret_cast<const float4*>(list2[al]);
    float acc0 = 0.f, acc1 = 0.f;
    for (int j = 0; j < mp; j += 8) {
        const float4 q0 = l4[(j >> 1) + 0];
        const float4 q1 = l4[(j >> 1) + 1];
        const float4 q2 = l4[(j >> 1) + 2];
        const float4 q3 = l4[(j >> 1) + 3];
        REC1(acc0, q0.x, q0.y) REC1(acc1, q0.z, q0.w)
        REC1(acc0, q1.x, q1.y) REC1(acc1, q1.z, q1.w)
        REC1(acc0, q2.x, q2.y) REC1(acc1, q2.z, q2.w)
        REC1(acc0, q3.x, q3.y) REC1(acc1, q3.z, q3.w)
    }
#undef REC1
    dens_bf[(size_t)a * NB + lane] = f2bf(acc0 + acc1);
}

// ---------------------------------------------------------------------------
// K3 nn via MFMA: R31 final (XCD-swizzled, dipole atomics folded in).
// ---------------------------------------------------------------------------
__global__ __launch_bounds__(256) void nn_kernel(
    const unsigned short* __restrict__ dens_bf, const float* __restrict__ tvv,
    const float* __restrict__ W1, const float* __restrict__ b1,
    const float* __restrict__ W2, const float* __restrict__ b2,
    float* __restrict__ dipole)
{
    __shared__ __align__(16) unsigned short w1t[HIDDEN * 72];
    __shared__ float b1_l[HIDDEN], w2_l[HIDDEN];
    __shared__ float sred[4][4][3];

    const int tid   = threadIdx.x;
    const int B     = blockIdx.x;
    const int mol   = B & 31;                  // XCD swizzle
    const int chunk = B >> 5;                  // 0..7

    for (int i = tid; i < NB * HIDDEN; i += 256) {
        const int k = i >> 8, j = i & 255;
        w1t[j * 72 + k] = f2bf(W1[i]);
    }
    if (tid < HIDDEN) { b1_l[tid] = b1[tid]; w2_l[tid] = W2[tid]; }
    __syncthreads();

    const int lane = tid & 63;
    const int wave = tid >> 6;
    const int fr   = lane & 15;
    const int fg   = lane >> 4;
    const int a0w  = mol * NATOM + chunk * 64 + wave * 16;

    bf16x8 afr[2];
#pragma unroll
    for (int kk = 0; kk < 2; ++kk)
        afr[kk] = *reinterpret_cast<const bf16x8*>(
            dens_bf + (size_t)(a0w + fr) * NB + kk * 32 + fg * 8);

    float sdip[4] = {0.f, 0.f, 0.f, 0.f};
#pragma unroll
    for (int nt = 0; nt < 16; ++nt) {
        const bf16x8 bf0 = *reinterpret_cast<const bf16x8*>(
            &w1t[(nt * 16 + fr) * 72 + 0 + fg * 8]);
        const bf16x8 bf1 = *reinterpret_cast<const bf16x8*>(
            &w1t[(nt * 16 + fr) * 72 + 32 + fg * 8]);
        f32x4 acc = {0.f, 0.f, 0.f, 0.f};
        acc = __builtin_amdgcn_mfma_f32_16x16x32_bf16(afr[0], bf0, acc, 0, 0, 0);
        acc = __builtin_amdgcn_mfma_f32_16x16x32_bf16(afr[1], bf1, acc, 0, 0, 0);
        const int j = nt * 16 + fr;
        const float b1v = b1_l[j], w2v = w2_l[j];
#pragma unroll
        for (int i = 0; i < 4; ++i) {
            const float h = acc[i] + b1v;
            sdip[i] += (h / (1.f + __expf(-h))) * w2v;
        }
    }
#pragma unroll
    for (int off = 1; off < 16; off <<= 1) {
#pragma unroll
        for (int i = 0; i < 4; ++i) sdip[i] += __shfl_xor(sdip[i], off);
    }
    if (fr == 0) {
        const float b2v = b2[0];
        float px = 0.f, py = 0.f, pz = 0.f;
#pragma unroll
        for (int i = 0; i < 4; ++i) {
            const int a = a0w + fg * 4 + i;
            const float out = sdip[i] + b2v;
            px += out * tvv[a * 3 + 0];
            py += out * tvv[a * 3 + 1];
            pz += out * tvv[a * 3 + 2];
        }
        sred[wave][fg][0] = px; sred[wave][fg][1] = py; sred[wave][fg][2] = pz;
    }
    __syncthreads();
    if (tid < 3) {
        float s = 0.f;
#pragma unroll
        for (int w = 0; w < 4; ++w)
#pragma unroll
            for (int g = 0; g < 4; ++g) s += sred[w][g][tid];
        unsafeAtomicAdd(&dipole[mol * 3 + tid], s);
    }
}

// ---------------------------------------------------------------------------
extern "C" void kernel_launch(void* const* d_in, const int* in_sizes, int n_in,
                              void* d_out, int out_size, void* d_ws, size_t ws_size,
                              hipStream_t stream)
{
    const float* cart       = (const float*)d_in[0];
    const float* shifts     = (const float*)d_in[1];
    const float* centers    = (const float*)d_in[2];
    const float* widths     = (const float*)d_in[3];
    const float* c_emb      = (const float*)d_in[4];
    const float* W1         = (const float*)d_in[5];
    const float* b1         = (const float*)d_in[6];
    const float* W2         = (const float*)d_in[7];
    const float* b2         = (const float*)d_in[8];
    const int*   species    = (const int*)d_in[10];
    const int*   atom_index = (const int*)d_in[11];

    // ws: cnt(512KB) | soff_g(512KB) | tvv(192KB) | tv_part(1.5MB) |
    //     dens_bf(2MB) | rec(5.8MB)
    unsigned*       cnt     = (unsigned*)d_ws;
    unsigned*       soff_g  = cnt + (size_t)TOTNATOM * NSUB;
    float*          tvv     = (float*)(soff_g + (size_t)NMOL * NSUB * NATOM);
    float*          tv_part = tvv + (size_t)TOTNATOM * 3;
    unsigned short* dens_bf = (unsigned short*)(tv_part + (size_t)NMOL * NSUB * NATOM * 3);
    float2*         rec     = (float2*)(dens_bf + (size_t)TOTNATOM * NB);
    float*          dipole  = (float*)d_out;

    hipLaunchKernelGGL(scatter_kernel, dim3(NMOL * NSUB), dim3(1024), 0, stream,
                       cart, shifts, species, atom_index, cnt, soff_g, rec,
                       tv_part, dipole, out_size);
    hipLaunchKernelGGL(gather_kernel, dim3(TOTNATOM / ABLK), dim3(256), 0, stream,
                       cnt, soff_g, rec, centers, widths, c_emb, tv_part,
                       dens_bf, tvv);
    hipLaunchKernelGGL(nn_kernel, dim3(TOTNATOM / 64), dim3(256), 0, stream,
                       dens_bf, tvv, W1, b1, W2, b2, dipole);
}